// Round 4
// baseline (134.909 us; speedup 1.0000x reference)
//
#include <hip/hip_runtime.h>
#include <math.h>

#define NB    8
#define NPTS  4096
#define NTH   1024
#define SPT   4
#define NFILT 128
#define MAXQ  512
#define MAXU  512
#define MAXK  256

__device__ __forceinline__ int blockReduceSumI(int v, int* scr, int tid) {
    #pragma unroll
    for (int o = 32; o > 0; o >>= 1) v += __shfl_down(v, o, 64);
    if ((tid & 63) == 0) scr[tid >> 6] = v;
    __syncthreads();
    if (tid == 0) {
        int s = 0;
        #pragma unroll
        for (int w = 0; w < NTH / 64; ++w) s += scr[w];
        scr[16] = s;
    }
    __syncthreads();
    return scr[16];
}

__device__ __forceinline__ float blockReduceSumF(float v, float* scr, int tid) {
    #pragma unroll
    for (int o = 32; o > 0; o >>= 1) v += __shfl_down(v, o, 64);
    if ((tid & 63) == 0) scr[tid >> 6] = v;
    __syncthreads();
    if (tid == 0) {
        float s = 0.0f;
        #pragma unroll
        for (int w = 0; w < NTH / 64; ++w) s += scr[w];
        scr[16] = s;
    }
    __syncthreads();
    return scr[16];
}

__device__ __forceinline__ float rowAngleDeg(float a0, float a1, float a2,
                                             float b0, float b1, float b2) {
    float dot = a0 * b0 + a1 * b1 + a2 * b2;
    float na = sqrtf(a0 * a0 + a1 * a1 + a2 * a2);
    float nb = sqrtf(b0 * b0 + b1 * b1 + b2 * b2);
    float c = dot / (na * nb);
    c = fminf(1.0f, fmaxf(-1.0f, c));
    return acosf(c) * 57.29577951308232f;  // /pi*180
}

// One block per batch. No sort: the conf-desc/idx-asc order is encoded in a
// u64 key; all "i precedes j" tests are key comparisons. All point data lives
// in registers (4 points/thread); LDS holds only small broadcast lists.
__global__ __launch_bounds__(NTH) void molan_kernel(const float* __restrict__ pred,
                                                    const float* __restrict__ targ,
                                                    float* __restrict__ out) {
    __shared__ int   scr_i[32];
    __shared__ float scr_f[32];
    __shared__ int   cnt[8];
    __shared__ unsigned long long f_key[NFILT];
    __shared__ float f_x[NFILT], f_y[NFILT], f_z[NFILT];
    __shared__ unsigned long long q_key[MAXQ];
    __shared__ float q_x[MAXQ], q_y[MAXQ], q_z[MAXQ];
    __shared__ int   q_res[MAXQ];
    __shared__ unsigned long long u_key[MAXU];
    __shared__ float u_x[MAXU], u_y[MAXU], u_z[MAXU];
    __shared__ float k_x[MAXK], k_y[MAXK], k_z[MAXK];
    __shared__ int   k_idx[MAXK];
    __shared__ unsigned int k_match[MAXK];

    const int b = blockIdx.x;
    const int tid = threadIdx.x;
    const float* pb = pred + (size_t)b * NPTS * 10;
    const float* tb = targ + (size_t)b * NPTS * 10;

    // ---- load preds: conf -> key, normalized positions (registers) ----
    unsigned long long key[SPT];
    bool  act[SPT];
    float cx[SPT], cy[SPT], cz[SPT];
    #pragma unroll
    for (int s = 0; s < SPT; ++s) {
        int n = 4 * tid + s;
        const float2* p2 = (const float2*)(pb + (size_t)n * 10);
        float2 A = p2[0];            // conf_raw, off_z
        float2 Bv = p2[1];           // off_x, off_y
        float conf = 1.0f / (1.0f + expf(-A.x));   // jax.nn.sigmoid
        act[s] = conf > 0.5f;
        unsigned int u = ~(__float_as_uint(conf) | 0x80000000u); // conf desc
        key[s] = ((unsigned long long)u << 32) | (unsigned int)n; // idx asc tiebreak
        float gz = (float)(n >> 10);
        float gx = (float)((n >> 5) & 31);
        float gy = (float)(n & 31);
        cx[s] = (A.y + gz) * 0.25f;
        cy[s] = (Bv.x + gx) * 0.03125f;
        cz[s] = (Bv.y + gy) * 0.03125f;
    }
    // ---- load targets: real coords (registers) ----
    bool  t_act[SPT];
    float t_x[SPT], t_y[SPT], t_z[SPT];
    int loc_ntg = 0;
    #pragma unroll
    for (int s = 0; s < SPT; ++s) {
        int n = 4 * tid + s;
        const float2* p2 = (const float2*)(tb + (size_t)n * 10);
        float2 A = p2[0];
        float2 Bv = p2[1];
        bool a = A.x > 0.5f;
        t_act[s] = a;
        if (a) ++loc_ntg;
        float gz = (float)(n >> 10);
        float gx = (float)((n >> 5) & 31);
        float gy = (float)(n & 31);
        t_x[s] = (A.y + gz) * 0.25f * 25.0f;
        t_y[s] = (Bv.x + gx) * 0.03125f * 25.0f;
        t_z[s] = (Bv.y + gy) * 0.03125f * 4.0f;
    }

    // ---- NMS fixpoint (exact reference semantics, order via keys) ----
    int loc = 0;
    #pragma unroll
    for (int s = 0; s < SPT; ++s) loc += act[s] ? 1 : 0;
    int cur = blockReduceSumI(loc, scr_i, tid);
    int prev = -1;
    while (cur != prev) {
        // build spatial filter: active points at every 32nd cell (<=128)
        if (tid == 0) cnt[0] = 0;
        __syncthreads();
        if ((tid & 7) == 0 && act[0]) {          // slot 4*tid+0 = 32*(tid/8)
            int e = atomicAdd(&cnt[0], 1);       // bounded by 128 candidates
            f_key[e] = key[0]; f_x[e] = cx[0]; f_y[e] = cy[0]; f_z[e] = cz[0];
        }
        __syncthreads();
        const int F = cnt[0];

        // pass 1: s[j] = exists active i (key_i<key_j) within cutoff
        bool sflag[SPT], pend[SPT];
        int pending = 0;
        #pragma unroll
        for (int s = 0; s < SPT; ++s) {
            sflag[s] = false; pend[s] = false;
            if (!act[s]) continue;
            bool found = false;
            for (int f = 0; f < F; ++f) {
                if (f_key[f] < key[s]) {
                    float dx = f_x[f] - cx[s], dy = f_y[f] - cy[s], dz = f_z[f] - cz[s];
                    if (dx * dx + dy * dy + dz * dz < 4.0f) { found = true; break; }
                }
            }
            if (found) sflag[s] = true;
            else { pend[s] = true; ++pending; }
        }
        // chunked cooperative resolve of unresolved points
        while (true) {
            int more = blockReduceSumI(pending, scr_i, tid);
            if (more == 0) break;
            if (tid == 0) cnt[1] = 0;
            __syncthreads();
            int qe[SPT];
            #pragma unroll
            for (int s = 0; s < SPT; ++s) {
                qe[s] = -1;
                if (pend[s]) {
                    int e = atomicAdd(&cnt[1], 1);
                    if (e < MAXQ) {
                        q_key[e] = key[s]; q_x[e] = cx[s]; q_y[e] = cy[s]; q_z[e] = cz[s];
                        q_res[e] = 0; qe[s] = e; pend[s] = false; --pending;
                    }
                }
            }
            __syncthreads();
            const int Q = min(cnt[1], MAXQ);
            for (int e = 0; e < Q; ++e) {
                unsigned long long qk = q_key[e];
                float qx = q_x[e], qy = q_y[e], qz = q_z[e];
                int hit = 0;
                #pragma unroll
                for (int s = 0; s < SPT; ++s) {
                    if (act[s] && key[s] < qk) {
                        float dx = cx[s] - qx, dy = cy[s] - qy, dz = cz[s] - qz;
                        if (dx * dx + dy * dy + dz * dz < 4.0f) hit = 1;
                    }
                }
                if (hit) atomicOr(&q_res[e], 1);
            }
            __syncthreads();
            #pragma unroll
            for (int s = 0; s < SPT; ++s)
                if (qe[s] >= 0) sflag[s] = (q_res[qe[s]] != 0);
        }

        // pass 2: supp[j] = exists u in U={active,!s} with key_u<key_j, d<cutoff
        bool upend[SPT], supp[SPT];
        int up = 0;
        #pragma unroll
        for (int s = 0; s < SPT; ++s) {
            upend[s] = act[s] && !sflag[s];
            up += upend[s] ? 1 : 0;
            supp[s] = false;
        }
        while (true) {
            int more = blockReduceSumI(up, scr_i, tid);
            if (more == 0) break;
            if (tid == 0) cnt[2] = 0;
            __syncthreads();
            #pragma unroll
            for (int s = 0; s < SPT; ++s) {
                if (upend[s]) {
                    int e = atomicAdd(&cnt[2], 1);
                    if (e < MAXU) {
                        u_key[e] = key[s]; u_x[e] = cx[s]; u_y[e] = cy[s]; u_z[e] = cz[s];
                        upend[s] = false; --up;
                    }
                }
            }
            __syncthreads();
            const int Ku = min(cnt[2], MAXU);
            #pragma unroll
            for (int s = 0; s < SPT; ++s) {
                if (!act[s] || supp[s]) continue;
                for (int e = 0; e < Ku; ++e) {
                    if (u_key[e] < key[s]) {
                        float dx = u_x[e] - cx[s], dy = u_y[e] - cy[s], dz = u_z[e] - cz[s];
                        if (dx * dx + dy * dy + dz * dz < 4.0f) { supp[s] = true; break; }
                    }
                }
            }
            // next chunk's overwrites are fenced by the reduce's barriers
        }
        // commit
        loc = 0;
        #pragma unroll
        for (int s = 0; s < SPT; ++s) {
            if (act[s] && supp[s]) act[s] = false;
            loc += act[s] ? 1 : 0;
        }
        prev = cur;
        cur = blockReduceSumI(loc, scr_i, tid);
    }
    const int n_pd = cur;

    // ---- matching: kept preds (chunked) vs all targets, lowest target idx ----
    bool kpend[SPT];
    int kp = 0;
    #pragma unroll
    for (int s = 0; s < SPT; ++s) { kpend[s] = act[s]; kp += act[s] ? 1 : 0; }
    int loc_tp = 0;
    float loc_ang = 0.0f;
    while (true) {
        int more = blockReduceSumI(kp, scr_i, tid);
        if (more == 0) break;
        if (tid == 0) cnt[3] = 0;
        __syncthreads();
        #pragma unroll
        for (int s = 0; s < SPT; ++s) {
            if (kpend[s]) {
                int e = atomicAdd(&cnt[3], 1);
                if (e < MAXK) {
                    k_x[e] = cx[s] * 25.0f; k_y[e] = cy[s] * 25.0f; k_z[e] = cz[s] * 4.0f;
                    k_idx[e] = 4 * tid + s;
                    k_match[e] = 0xFFFFFFFFu;
                    kpend[s] = false; --kp;
                }
            }
        }
        __syncthreads();
        const int K = min(cnt[3], MAXK);
        #pragma unroll
        for (int s = 0; s < SPT; ++s) {
            if (!t_act[s]) continue;
            int n = 4 * tid + s;
            float tx = t_x[s], ty = t_y[s], tz = t_z[s];
            for (int e = 0; e < K; ++e) {
                float dx = tx - k_x[e], dy = ty - k_y[e], dz = tz - k_z[e];
                if (dx * dx + dy * dy + dz * dz < 4.0f)
                    atomicMin(&k_match[e], (unsigned int)n);
            }
        }
        __syncthreads();
        if (tid < K) {
            unsigned int m = k_match[tid];
            if (m != 0xFFFFFFFFu) {
                ++loc_tp;
                const float* pr = pb + (size_t)k_idx[tid] * 10;
                float ax0 = pr[4], ax1 = pr[5], ax2 = pr[6];
                float ay0 = pr[7], ay1 = pr[8], ay2 = pr[9];
                float az0 = ax1 * ay2 - ax2 * ay1;
                float az1 = ax2 * ay0 - ax0 * ay2;
                float az2 = ax0 * ay1 - ax1 * ay0;
                const float* tr = tb + (size_t)m * 10;
                float bx0 = tr[4], bx1 = tr[5], bx2 = tr[6];
                float by0 = tr[7], by1 = tr[8], by2 = tr[9];
                float bz0 = bx1 * by2 - bx2 * by1;
                float bz1 = bx2 * by0 - bx0 * by2;
                float bz2 = bx0 * by1 - bx1 * by0;
                loc_ang += rowAngleDeg(ax0, ax1, ax2, bx0, bx1, bx2);
                loc_ang += rowAngleDeg(ay0, ay1, ay2, by0, by1, by2);
                loc_ang += rowAngleDeg(az0, az1, az2, bz0, bz1, bz2);
            }
        }
        __syncthreads();  // k_match reads done before next chunk reuses region
    }

    int n_tg = blockReduceSumI(loc_ntg, scr_i, tid);
    int tp   = blockReduceSumI(loc_tp,  scr_i, tid);
    float angsum = blockReduceSumF(loc_ang, scr_f, tid);

    if (tid == 0) {
        out[b * 3 + 0] = (float)tp;
        out[b * 3 + 1] = (float)(n_pd - tp);
        out[b * 3 + 2] = (float)(n_tg - tp);
        out[NB * 3 + b] = (tp > 0) ? (angsum / (3.0f * (float)tp)) : 0.0f;
    }
}

extern "C" void kernel_launch(void* const* d_in, const int* in_sizes, int n_in,
                              void* d_out, int out_size, void* d_ws, size_t ws_size,
                              hipStream_t stream) {
    const float* pred = (const float*)d_in[0];
    const float* targ = (const float*)d_in[1];
    float* out = (float*)d_out;
    molan_kernel<<<dim3(NB), dim3(NTH), 0, stream>>>(pred, targ, out);
}

// Round 5
// 82.890 us; speedup vs baseline: 1.6276x; 1.6276x over previous
//
#include <hip/hip_runtime.h>
#include <math.h>

#define NB    8
#define NPTS  4096
#define NTH   1024
#define SPT   4
#define NFILT 16
#define MAXQ  64          // queue chunk == bits in the hit mask
#define MAXU  256
#define MAXK  256

__device__ __forceinline__ int blockReduceSumI(int v, int* scr, int tid) {
    #pragma unroll
    for (int o = 32; o > 0; o >>= 1) v += __shfl_down(v, o, 64);
    if ((tid & 63) == 0) scr[tid >> 6] = v;
    __syncthreads();
    if (tid == 0) {
        int s = 0;
        #pragma unroll
        for (int w = 0; w < NTH / 64; ++w) s += scr[w];
        scr[16] = s;
    }
    __syncthreads();
    return scr[16];
}

__device__ __forceinline__ float blockReduceSumF(float v, float* scr, int tid) {
    #pragma unroll
    for (int o = 32; o > 0; o >>= 1) v += __shfl_down(v, o, 64);
    if ((tid & 63) == 0) scr[tid >> 6] = v;
    __syncthreads();
    if (tid == 0) {
        float s = 0.0f;
        #pragma unroll
        for (int w = 0; w < NTH / 64; ++w) s += scr[w];
        scr[16] = s;
    }
    __syncthreads();
    return scr[16];
}

__device__ __forceinline__ float rowAngleDeg(float a0, float a1, float a2,
                                             float b0, float b1, float b2) {
    float dot = a0 * b0 + a1 * b1 + a2 * b2;
    float na = sqrtf(a0 * a0 + a1 * a1 + a2 * a2);
    float nb = sqrtf(b0 * b0 + b1 * b1 + b2 * b2);
    float c = dot / (na * nb);
    c = fminf(1.0f, fmaxf(-1.0f, c));
    return acosf(c) * 57.29577951308232f;  // /pi*180
}

// One block per batch. Sort-free: conf-desc/idx-asc order lives in a u64 key;
// "i precedes j" is a key comparison. Points in registers (4/thread); LDS only
// holds small broadcast lists. No same-address LDS atomics on hot paths.
__global__ __launch_bounds__(NTH) void molan_kernel(const float* __restrict__ pred,
                                                    const float* __restrict__ targ,
                                                    float* __restrict__ out) {
    __shared__ int   scr_i[32];
    __shared__ float scr_f[32];
    __shared__ unsigned long long scr_m[16];
    __shared__ int   cnt[8];
    __shared__ unsigned long long f_key[NFILT];
    __shared__ float f_x[NFILT], f_y[NFILT], f_z[NFILT];
    __shared__ unsigned long long q_key[MAXQ];
    __shared__ float q_x[MAXQ], q_y[MAXQ], q_z[MAXQ];
    __shared__ unsigned long long u_key[MAXU];
    __shared__ float u_x[MAXU], u_y[MAXU], u_z[MAXU];
    __shared__ float k_x[MAXK], k_y[MAXK], k_z[MAXK];
    __shared__ int   k_idx[MAXK];
    __shared__ unsigned int k_match[MAXK];

    const int b = blockIdx.x;
    const int tid = threadIdx.x;
    const float* pb = pred + (size_t)b * NPTS * 10;
    const float* tb = targ + (size_t)b * NPTS * 10;

    // ---- load preds: conf -> key, normalized positions (registers) ----
    unsigned long long key[SPT];
    bool  act[SPT];
    float cx[SPT], cy[SPT], cz[SPT];
    #pragma unroll
    for (int s = 0; s < SPT; ++s) {
        int n = 4 * tid + s;
        const float2* p2 = (const float2*)(pb + (size_t)n * 10);
        float2 A = p2[0];            // conf_raw, off_z
        float2 Bv = p2[1];           // off_x, off_y
        float conf = 1.0f / (1.0f + expf(-A.x));   // jax.nn.sigmoid
        act[s] = conf > 0.5f;
        unsigned int u = ~(__float_as_uint(conf) | 0x80000000u); // conf desc
        key[s] = ((unsigned long long)u << 32) | (unsigned int)n; // idx asc tiebreak
        float gz = (float)(n >> 10);
        float gx = (float)((n >> 5) & 31);
        float gy = (float)(n & 31);
        cx[s] = (A.y + gz) * 0.25f;
        cy[s] = (Bv.x + gx) * 0.03125f;
        cz[s] = (Bv.y + gy) * 0.03125f;
    }
    // ---- load targets: real coords (registers) ----
    bool  t_act[SPT];
    float t_x[SPT], t_y[SPT], t_z[SPT];
    int loc_ntg = 0;
    #pragma unroll
    for (int s = 0; s < SPT; ++s) {
        int n = 4 * tid + s;
        const float2* p2 = (const float2*)(tb + (size_t)n * 10);
        float2 A = p2[0];
        float2 Bv = p2[1];
        bool a = A.x > 0.5f;
        t_act[s] = a;
        if (a) ++loc_ntg;
        float gz = (float)(n >> 10);
        float gx = (float)((n >> 5) & 31);
        float gy = (float)(n & 31);
        t_x[s] = (A.y + gz) * 0.25f * 25.0f;
        t_y[s] = (Bv.x + gx) * 0.03125f * 25.0f;
        t_z[s] = (Bv.y + gy) * 0.03125f * 4.0f;
    }

    // ---- NMS fixpoint (exact reference semantics, order via keys) ----
    int loc = 0;
    #pragma unroll
    for (int s = 0; s < SPT; ++s) loc += act[s] ? 1 : 0;
    int cur = blockReduceSumI(loc, scr_i, tid);
    int prev = -1;
    while (cur != prev) {
        // filter = per-wave confidence champion (min key among actives)
        if (tid == 0) cnt[0] = 0;
        __syncthreads();
        {
            unsigned long long bk = ~0ull;
            float bx = 0.f, by = 0.f, bz = 0.f;
            #pragma unroll
            for (int s = 0; s < SPT; ++s)
                if (act[s] && key[s] < bk) { bk = key[s]; bx = cx[s]; by = cy[s]; bz = cz[s]; }
            #pragma unroll
            for (int o = 32; o > 0; o >>= 1) {
                unsigned long long ok = __shfl_xor(bk, o, 64);
                float ox = __shfl_xor(bx, o, 64);
                float oy = __shfl_xor(by, o, 64);
                float oz = __shfl_xor(bz, o, 64);
                if (ok < bk) { bk = ok; bx = ox; by = oy; bz = oz; }
            }
            if ((tid & 63) == 0 && bk != ~0ull) {
                int e = atomicAdd(&cnt[0], 1);   // <=16, one per wave
                f_key[e] = bk; f_x[e] = bx; f_y[e] = by; f_z[e] = bz;
            }
        }
        __syncthreads();
        const int F = cnt[0];

        // pass 1: s[j] = exists active i (key_i<key_j) within cutoff
        bool sflag[SPT], pend[SPT];
        int pending = 0;
        #pragma unroll
        for (int s = 0; s < SPT; ++s) {
            sflag[s] = false; pend[s] = false;
            if (!act[s]) continue;
            bool found = false;
            for (int f = 0; f < F; ++f) {
                if (f_key[f] < key[s]) {
                    float dx = f_x[f] - cx[s], dy = f_y[f] - cy[s], dz = f_z[f] - cz[s];
                    if (dx * dx + dy * dy + dz * dz < 4.0f) { found = true; break; }
                }
            }
            if (found) sflag[s] = true;
            else { pend[s] = true; ++pending; }
        }
        // chunked cooperative resolve, hit-mask reduction (no atomics)
        while (true) {
            int more = blockReduceSumI(pending, scr_i, tid);
            if (more == 0) break;
            if (tid == 0) cnt[1] = 0;
            __syncthreads();
            int qe[SPT];
            #pragma unroll
            for (int s = 0; s < SPT; ++s) {
                qe[s] = -1;
                if (pend[s]) {
                    int e = atomicAdd(&cnt[1], 1);
                    if (e < MAXQ) {
                        q_key[e] = key[s]; q_x[e] = cx[s]; q_y[e] = cy[s]; q_z[e] = cz[s];
                        qe[s] = e; pend[s] = false; --pending;
                    }
                }
            }
            __syncthreads();
            const int Q = min(cnt[1], MAXQ);
            unsigned long long mask = 0;
            for (int e = 0; e < Q; ++e) {     // uniform loop, all lanes present
                unsigned long long qk = q_key[e];
                float qx = q_x[e], qy = q_y[e], qz = q_z[e];
                bool hit = false;
                #pragma unroll
                for (int s = 0; s < SPT; ++s) {
                    if (act[s] && key[s] < qk) {
                        float dx = cx[s] - qx, dy = cy[s] - qy, dz = cz[s] - qz;
                        if (dx * dx + dy * dy + dz * dz < 4.0f) hit = true;
                    }
                }
                if (hit) mask |= (1ull << e);
            }
            #pragma unroll
            for (int o = 32; o > 0; o >>= 1) mask |= __shfl_xor(mask, o, 64);
            if ((tid & 63) == 0) scr_m[tid >> 6] = mask;
            __syncthreads();
            unsigned long long full = 0;
            #pragma unroll
            for (int w = 0; w < NTH / 64; ++w) full |= scr_m[w];
            #pragma unroll
            for (int s = 0; s < SPT; ++s)
                if (qe[s] >= 0) sflag[s] = (full >> qe[s]) & 1ull;
            __syncthreads();  // mask reads done before next chunk rewrites
        }

        // pass 2: supp[j] = exists u in U={active,!s} with key_u<key_j, d<cutoff
        bool upend[SPT], supp[SPT];
        int up = 0;
        #pragma unroll
        for (int s = 0; s < SPT; ++s) {
            upend[s] = act[s] && !sflag[s];
            up += upend[s] ? 1 : 0;
            supp[s] = false;
        }
        while (true) {
            int more = blockReduceSumI(up, scr_i, tid);
            if (more == 0) break;
            if (tid == 0) cnt[2] = 0;
            __syncthreads();
            #pragma unroll
            for (int s = 0; s < SPT; ++s) {
                if (upend[s]) {
                    int e = atomicAdd(&cnt[2], 1);
                    if (e < MAXU) {
                        u_key[e] = key[s]; u_x[e] = cx[s]; u_y[e] = cy[s]; u_z[e] = cz[s];
                        upend[s] = false; --up;
                    }
                }
            }
            __syncthreads();
            const int Ku = min(cnt[2], MAXU);
            #pragma unroll
            for (int s = 0; s < SPT; ++s) {
                if (!act[s] || supp[s]) continue;
                for (int e = 0; e < Ku; ++e) {
                    if (u_key[e] < key[s]) {
                        float dx = u_x[e] - cx[s], dy = u_y[e] - cy[s], dz = u_z[e] - cz[s];
                        if (dx * dx + dy * dy + dz * dz < 4.0f) { supp[s] = true; break; }
                    }
                }
            }
            __syncthreads();  // u reads done before next chunk rewrites
        }
        // commit
        loc = 0;
        #pragma unroll
        for (int s = 0; s < SPT; ++s) {
            if (act[s] && supp[s]) act[s] = false;
            loc += act[s] ? 1 : 0;
        }
        prev = cur;
        cur = blockReduceSumI(loc, scr_i, tid);
    }
    const int n_pd = cur;

    // ---- matching: kept preds (chunked) vs all targets, lowest target idx ----
    bool kpend[SPT];
    int kp = 0;
    #pragma unroll
    for (int s = 0; s < SPT; ++s) { kpend[s] = act[s]; kp += act[s] ? 1 : 0; }
    int loc_tp = 0;
    float loc_ang = 0.0f;
    while (true) {
        int more = blockReduceSumI(kp, scr_i, tid);
        if (more == 0) break;
        if (tid == 0) cnt[3] = 0;
        __syncthreads();
        #pragma unroll
        for (int s = 0; s < SPT; ++s) {
            if (kpend[s]) {
                int e = atomicAdd(&cnt[3], 1);
                if (e < MAXK) {
                    k_x[e] = cx[s] * 25.0f; k_y[e] = cy[s] * 25.0f; k_z[e] = cz[s] * 4.0f;
                    k_idx[e] = 4 * tid + s;
                    k_match[e] = 0xFFFFFFFFu;
                    kpend[s] = false; --kp;
                }
            }
        }
        __syncthreads();
        const int K = min(cnt[3], MAXK);
        #pragma unroll
        for (int s = 0; s < SPT; ++s) {
            if (!t_act[s]) continue;
            int n = 4 * tid + s;
            float tx = t_x[s], ty = t_y[s], tz = t_z[s];
            for (int e = 0; e < K; ++e) {
                float dx = tx - k_x[e], dy = ty - k_y[e], dz = tz - k_z[e];
                if (dx * dx + dy * dy + dz * dz < 4.0f)
                    atomicMin(&k_match[e], (unsigned int)n);  // few hits, cheap
            }
        }
        __syncthreads();
        if (tid < K) {
            unsigned int m = k_match[tid];
            if (m != 0xFFFFFFFFu) {
                ++loc_tp;
                const float2* pr = (const float2*)(pb + (size_t)k_idx[tid] * 10 + 4);
                float2 p0 = pr[0], p1 = pr[1], p2v = pr[2];
                float ax0 = p0.x, ax1 = p0.y, ax2 = p1.x;
                float ay0 = p1.y, ay1 = p2v.x, ay2 = p2v.y;
                float az0 = ax1 * ay2 - ax2 * ay1;
                float az1 = ax2 * ay0 - ax0 * ay2;
                float az2 = ax0 * ay1 - ax1 * ay0;
                const float2* tr = (const float2*)(tb + (size_t)m * 10 + 4);
                float2 t0 = tr[0], t1 = tr[1], t2v = tr[2];
                float bx0 = t0.x, bx1 = t0.y, bx2 = t1.x;
                float by0 = t1.y, by1 = t2v.x, by2 = t2v.y;
                float bz0 = bx1 * by2 - bx2 * by1;
                float bz1 = bx2 * by0 - bx0 * by2;
                float bz2 = bx0 * by1 - bx1 * by0;
                loc_ang += rowAngleDeg(ax0, ax1, ax2, bx0, bx1, bx2);
                loc_ang += rowAngleDeg(ay0, ay1, ay2, by0, by1, by2);
                loc_ang += rowAngleDeg(az0, az1, az2, bz0, bz1, bz2);
            }
        }
        __syncthreads();  // k_match reads done before next chunk reuses region
    }

    int n_tg = blockReduceSumI(loc_ntg, scr_i, tid);
    int tp   = blockReduceSumI(loc_tp,  scr_i, tid);
    float angsum = blockReduceSumF(loc_ang, scr_f, tid);

    if (tid == 0) {
        out[b * 3 + 0] = (float)tp;
        out[b * 3 + 1] = (float)(n_pd - tp);
        out[b * 3 + 2] = (float)(n_tg - tp);
        out[NB * 3 + b] = (tp > 0) ? (angsum / (3.0f * (float)tp)) : 0.0f;
    }
}

extern "C" void kernel_launch(void* const* d_in, const int* in_sizes, int n_in,
                              void* d_out, int out_size, void* d_ws, size_t ws_size,
                              hipStream_t stream) {
    const float* pred = (const float*)d_in[0];
    const float* targ = (const float*)d_in[1];
    float* out = (float*)d_out;
    molan_kernel<<<dim3(NB), dim3(NTH), 0, stream>>>(pred, targ, out);
}

// Round 6
// 82.840 us; speedup vs baseline: 1.6285x; 1.0006x over previous
//
#include <hip/hip_runtime.h>
#include <math.h>

#define NB    8
#define NPTS  4096
#define NTH   1024
#define SPT   4
#define NFILT 16
#define MAXQ  64          // queue chunk == bits in the hit mask
#define MAXU  256
#define MAXK  256

__device__ __forceinline__ int blockReduceSumI(int v, int* scr, int tid) {
    #pragma unroll
    for (int o = 32; o > 0; o >>= 1) v += __shfl_down(v, o, 64);
    if ((tid & 63) == 0) scr[tid >> 6] = v;
    __syncthreads();
    if (tid == 0) {
        int s = 0;
        #pragma unroll
        for (int w = 0; w < NTH / 64; ++w) s += scr[w];
        scr[16] = s;
    }
    __syncthreads();
    return scr[16];
}

__device__ __forceinline__ float blockReduceSumF(float v, float* scr, int tid) {
    #pragma unroll
    for (int o = 32; o > 0; o >>= 1) v += __shfl_down(v, o, 64);
    if ((tid & 63) == 0) scr[tid >> 6] = v;
    __syncthreads();
    if (tid == 0) {
        float s = 0.0f;
        #pragma unroll
        for (int w = 0; w < NTH / 64; ++w) s += scr[w];
        scr[16] = s;
    }
    __syncthreads();
    return scr[16];
}

__device__ __forceinline__ float rowAngleDeg(float a0, float a1, float a2,
                                             float b0, float b1, float b2) {
    float dot = a0 * b0 + a1 * b1 + a2 * b2;
    float na = sqrtf(a0 * a0 + a1 * a1 + a2 * a2);
    float nb = sqrtf(b0 * b0 + b1 * b1 + b2 * b2);
    float c = dot / (na * nb);
    c = fminf(1.0f, fmaxf(-1.0f, c));
    return acosf(c) * 57.29577951308232f;  // /pi*180
}

// One block per batch. Sort-free NMS: conf-desc/idx-asc order lives in a u64
// key; "i precedes j" is a key compare. Point p = tid + 1024*s lives in
// registers. Inputs staged through LDS in 40 KB coalesced float4 quarters
// (strided 40 B/point direct loads cost ~17 us; staging ~4 us).
__global__ __launch_bounds__(NTH) void molan_kernel(const float* __restrict__ pred,
                                                    const float* __restrict__ targ,
                                                    float* __restrict__ out) {
    __shared__ float4 stage[2560];           // 40 KB staging buffer
    __shared__ int   scr_i[32];
    __shared__ float scr_f[32];
    __shared__ unsigned long long scr_m[16];
    __shared__ int   cnt[8];
    __shared__ unsigned long long f_key[NFILT];
    __shared__ float f_x[NFILT], f_y[NFILT], f_z[NFILT];
    __shared__ unsigned long long q_key[MAXQ];
    __shared__ float q_x[MAXQ], q_y[MAXQ], q_z[MAXQ];
    __shared__ unsigned long long u_key[MAXU];
    __shared__ float u_x[MAXU], u_y[MAXU], u_z[MAXU];
    __shared__ float k_x[MAXK], k_y[MAXK], k_z[MAXK];
    __shared__ int   k_idx[MAXK];
    __shared__ unsigned int k_match[MAXK];

    const int b = blockIdx.x;
    const int tid = threadIdx.x;
    const float* pb = pred + (size_t)b * NPTS * 10;
    const float* tb = targ + (size_t)b * NPTS * 10;
    const float* sf = (const float*)stage;

    // ---- stage pred through LDS, extract key/act/pos (point p = tid+1024q) ----
    unsigned long long key[SPT];
    bool  act[SPT];
    float cx[SPT], cy[SPT], cz[SPT];
    {
        const float4* g4 = (const float4*)pb;   // 2560 float4 per quarter
        float4 r0 = g4[tid], r1 = g4[tid + 1024], r2;
        if (tid < 512) r2 = g4[tid + 2048];
        for (int q = 0; q < 4; ++q) {
            stage[tid] = r0;
            stage[tid + 1024] = r1;
            if (tid < 512) stage[tid + 2048] = r2;
            __syncthreads();
            if (q < 3) {                         // prefetch next quarter
                int base = 2560 * (q + 1);
                r0 = g4[base + tid];
                r1 = g4[base + tid + 1024];
                if (tid < 512) r2 = g4[base + tid + 2048];
            }
            int n = tid + 1024 * q;
            float conf_raw = sf[10 * tid + 0];
            float oz = sf[10 * tid + 1];
            float ox = sf[10 * tid + 2];
            float oy = sf[10 * tid + 3];
            float conf = 1.0f / (1.0f + expf(-conf_raw));   // jax.nn.sigmoid
            act[q] = conf > 0.5f;
            unsigned int u = ~(__float_as_uint(conf) | 0x80000000u); // conf desc
            key[q] = ((unsigned long long)u << 32) | (unsigned int)n;
            float gz = (float)(n >> 10);
            float gx = (float)((n >> 5) & 31);
            float gy = (float)(n & 31);
            cx[q] = (oz + gz) * 0.25f;
            cy[q] = (ox + gx) * 0.03125f;
            cz[q] = (oy + gy) * 0.03125f;
            __syncthreads();
        }
    }
    // ---- stage targ, extract active/real-pos ----
    bool  t_act[SPT];
    float t_x[SPT], t_y[SPT], t_z[SPT];
    int loc_ntg = 0;
    {
        const float4* g4 = (const float4*)tb;
        float4 r0 = g4[tid], r1 = g4[tid + 1024], r2;
        if (tid < 512) r2 = g4[tid + 2048];
        for (int q = 0; q < 4; ++q) {
            stage[tid] = r0;
            stage[tid + 1024] = r1;
            if (tid < 512) stage[tid + 2048] = r2;
            __syncthreads();
            if (q < 3) {
                int base = 2560 * (q + 1);
                r0 = g4[base + tid];
                r1 = g4[base + tid + 1024];
                if (tid < 512) r2 = g4[base + tid + 2048];
            }
            int n = tid + 1024 * q;
            float tc = sf[10 * tid + 0];
            float oz = sf[10 * tid + 1];
            float ox = sf[10 * tid + 2];
            float oy = sf[10 * tid + 3];
            bool a = tc > 0.5f;
            t_act[q] = a;
            if (a) ++loc_ntg;
            float gz = (float)(n >> 10);
            float gx = (float)((n >> 5) & 31);
            float gy = (float)(n & 31);
            t_x[q] = (oz + gz) * 0.25f * 25.0f;
            t_y[q] = (ox + gx) * 0.03125f * 25.0f;
            t_z[q] = (oy + gy) * 0.03125f * 4.0f;
            __syncthreads();
        }
    }

    // ---- NMS fixpoint (exact reference semantics, order via keys) ----
    int loc = 0;
    #pragma unroll
    for (int s = 0; s < SPT; ++s) loc += act[s] ? 1 : 0;
    int cur = blockReduceSumI(loc, scr_i, tid);
    int prev = -1;
    while (cur != prev) {
        // filter = per-wave confidence champion (min key among actives);
        // waves with no active write sentinel ~0ull (never precedes anything)
        {
            unsigned long long bk = ~0ull;
            float bx = 0.f, by = 0.f, bz = 0.f;
            #pragma unroll
            for (int s = 0; s < SPT; ++s)
                if (act[s] && key[s] < bk) { bk = key[s]; bx = cx[s]; by = cy[s]; bz = cz[s]; }
            #pragma unroll
            for (int o = 32; o > 0; o >>= 1) {
                unsigned long long ok = __shfl_xor(bk, o, 64);
                float ox = __shfl_xor(bx, o, 64);
                float oy = __shfl_xor(by, o, 64);
                float oz = __shfl_xor(bz, o, 64);
                if (ok < bk) { bk = ok; bx = ox; by = oy; bz = oz; }
            }
            if ((tid & 63) == 0) {
                int w = tid >> 6;
                f_key[w] = bk; f_x[w] = bx; f_y[w] = by; f_z[w] = bz;
            }
        }
        __syncthreads();

        // pass 1: s[j] = exists active i (key_i<key_j) within cutoff
        bool sflag[SPT], pend[SPT];
        int pending = 0;
        #pragma unroll
        for (int s = 0; s < SPT; ++s) {
            sflag[s] = false; pend[s] = false;
            if (!act[s]) continue;
            bool found = false;
            for (int f = 0; f < NFILT; ++f) {
                if (f_key[f] < key[s]) {
                    float dx = f_x[f] - cx[s], dy = f_y[f] - cy[s], dz = f_z[f] - cz[s];
                    if (dx * dx + dy * dy + dz * dz < 4.0f) { found = true; break; }
                }
            }
            if (found) sflag[s] = true;
            else { pend[s] = true; ++pending; }
        }
        // chunked cooperative resolve, hit-mask reduction (no same-addr atomics)
        while (true) {
            int more = blockReduceSumI(pending, scr_i, tid);
            if (more == 0) break;
            if (tid == 0) cnt[1] = 0;
            __syncthreads();
            int qe[SPT];
            #pragma unroll
            for (int s = 0; s < SPT; ++s) {
                qe[s] = -1;
                if (pend[s]) {
                    int e = atomicAdd(&cnt[1], 1);
                    if (e < MAXQ) {
                        q_key[e] = key[s]; q_x[e] = cx[s]; q_y[e] = cy[s]; q_z[e] = cz[s];
                        qe[s] = e; pend[s] = false; --pending;
                    }
                }
            }
            __syncthreads();
            const int Q = min(cnt[1], MAXQ);
            unsigned long long mask = 0;
            for (int e = 0; e < Q; ++e) {     // uniform loop, all lanes present
                unsigned long long qk = q_key[e];
                float qx = q_x[e], qy = q_y[e], qz = q_z[e];
                bool hit = false;
                #pragma unroll
                for (int s = 0; s < SPT; ++s) {
                    if (act[s] && key[s] < qk) {
                        float dx = cx[s] - qx, dy = cy[s] - qy, dz = cz[s] - qz;
                        if (dx * dx + dy * dy + dz * dz < 4.0f) hit = true;
                    }
                }
                if (hit) mask |= (1ull << e);
            }
            #pragma unroll
            for (int o = 32; o > 0; o >>= 1) mask |= __shfl_xor(mask, o, 64);
            if ((tid & 63) == 0) scr_m[tid >> 6] = mask;
            __syncthreads();
            unsigned long long full = 0;
            #pragma unroll
            for (int w = 0; w < NTH / 64; ++w) full |= scr_m[w];
            #pragma unroll
            for (int s = 0; s < SPT; ++s)
                if (qe[s] >= 0) sflag[s] = (full >> qe[s]) & 1ull;
            __syncthreads();  // mask reads done before next chunk rewrites
        }

        // pass 2: supp[j] = exists u in U={active,!s} with key_u<key_j, d<cutoff
        bool upend[SPT], supp[SPT];
        int up = 0;
        #pragma unroll
        for (int s = 0; s < SPT; ++s) {
            upend[s] = act[s] && !sflag[s];
            up += upend[s] ? 1 : 0;
            supp[s] = false;
        }
        while (true) {
            int more = blockReduceSumI(up, scr_i, tid);
            if (more == 0) break;
            if (tid == 0) cnt[2] = 0;
            __syncthreads();
            #pragma unroll
            for (int s = 0; s < SPT; ++s) {
                if (upend[s]) {
                    int e = atomicAdd(&cnt[2], 1);
                    if (e < MAXU) {
                        u_key[e] = key[s]; u_x[e] = cx[s]; u_y[e] = cy[s]; u_z[e] = cz[s];
                        upend[s] = false; --up;
                    }
                }
            }
            __syncthreads();
            const int Ku = min(cnt[2], MAXU);
            #pragma unroll
            for (int s = 0; s < SPT; ++s) {
                if (!act[s] || supp[s]) continue;
                for (int e = 0; e < Ku; ++e) {
                    if (u_key[e] < key[s]) {
                        float dx = u_x[e] - cx[s], dy = u_y[e] - cy[s], dz = u_z[e] - cz[s];
                        if (dx * dx + dy * dy + dz * dz < 4.0f) { supp[s] = true; break; }
                    }
                }
            }
            __syncthreads();  // u reads done before next chunk rewrites
        }
        // commit
        loc = 0;
        #pragma unroll
        for (int s = 0; s < SPT; ++s) {
            if (act[s] && supp[s]) act[s] = false;
            loc += act[s] ? 1 : 0;
        }
        prev = cur;
        cur = blockReduceSumI(loc, scr_i, tid);
    }
    const int n_pd = cur;

    // ---- matching: kept preds (chunked) vs all targets, lowest target idx ----
    bool kpend[SPT];
    int kp = 0;
    #pragma unroll
    for (int s = 0; s < SPT; ++s) { kpend[s] = act[s]; kp += act[s] ? 1 : 0; }
    int loc_tp = 0;
    float loc_ang = 0.0f;
    while (true) {
        int more = blockReduceSumI(kp, scr_i, tid);
        if (more == 0) break;
        if (tid == 0) cnt[3] = 0;
        __syncthreads();
        #pragma unroll
        for (int s = 0; s < SPT; ++s) {
            if (kpend[s]) {
                int e = atomicAdd(&cnt[3], 1);
                if (e < MAXK) {
                    k_x[e] = cx[s] * 25.0f; k_y[e] = cy[s] * 25.0f; k_z[e] = cz[s] * 4.0f;
                    k_idx[e] = tid + 1024 * s;
                    k_match[e] = 0xFFFFFFFFu;
                    kpend[s] = false; --kp;
                }
            }
        }
        __syncthreads();
        const int K = min(cnt[3], MAXK);
        #pragma unroll
        for (int s = 0; s < SPT; ++s) {
            if (!t_act[s]) continue;
            int n = tid + 1024 * s;
            float tx = t_x[s], ty = t_y[s], tz = t_z[s];
            for (int e = 0; e < K; ++e) {
                float dx = tx - k_x[e], dy = ty - k_y[e], dz = tz - k_z[e];
                if (dx * dx + dy * dy + dz * dz < 4.0f)
                    atomicMin(&k_match[e], (unsigned int)n);  // few hits, cheap
            }
        }
        __syncthreads();
        if (tid < K) {
            unsigned int m = k_match[tid];
            if (m != 0xFFFFFFFFu) {
                ++loc_tp;
                const float2* pr = (const float2*)(pb + (size_t)k_idx[tid] * 10 + 4);
                float2 p0 = pr[0], p1 = pr[1], p2v = pr[2];
                float ax0 = p0.x, ax1 = p0.y, ax2 = p1.x;
                float ay0 = p1.y, ay1 = p2v.x, ay2 = p2v.y;
                float az0 = ax1 * ay2 - ax2 * ay1;
                float az1 = ax2 * ay0 - ax0 * ay2;
                float az2 = ax0 * ay1 - ax1 * ay0;
                const float2* tr = (const float2*)(tb + (size_t)m * 10 + 4);
                float2 t0 = tr[0], t1 = tr[1], t2v = tr[2];
                float bx0 = t0.x, bx1 = t0.y, bx2 = t1.x;
                float by0 = t1.y, by1 = t2v.x, by2 = t2v.y;
                float bz0 = bx1 * by2 - bx2 * by1;
                float bz1 = bx2 * by0 - bx0 * by2;
                float bz2 = bx0 * by1 - bx1 * by0;
                loc_ang += rowAngleDeg(ax0, ax1, ax2, bx0, bx1, bx2);
                loc_ang += rowAngleDeg(ay0, ay1, ay2, by0, by1, by2);
                loc_ang += rowAngleDeg(az0, az1, az2, bz0, bz1, bz2);
            }
        }
        __syncthreads();  // k_match reads done before next chunk reuses region
    }

    int n_tg = blockReduceSumI(loc_ntg, scr_i, tid);
    int tp   = blockReduceSumI(loc_tp,  scr_i, tid);
    float angsum = blockReduceSumF(loc_ang, scr_f, tid);

    if (tid == 0) {
        out[b * 3 + 0] = (float)tp;
        out[b * 3 + 1] = (float)(n_pd - tp);
        out[b * 3 + 2] = (float)(n_tg - tp);
        out[NB * 3 + b] = (tp > 0) ? (angsum / (3.0f * (float)tp)) : 0.0f;
    }
}

extern "C" void kernel_launch(void* const* d_in, const int* in_sizes, int n_in,
                              void* d_out, int out_size, void* d_ws, size_t ws_size,
                              hipStream_t stream) {
    const float* pred = (const float*)d_in[0];
    const float* targ = (const float*)d_in[1];
    float* out = (float*)d_out;
    molan_kernel<<<dim3(NB), dim3(NTH), 0, stream>>>(pred, targ, out);
}